// Round 10
// baseline (9192.353 us; speedup 1.0000x reference)
//
#include <hip/hip_runtime.h>
#include <hip/hip_cooperative_groups.h>

typedef unsigned short ushort_t;
typedef __attribute__((ext_vector_type(8))) short bf16x8;
typedef __attribute__((ext_vector_type(4))) float f32x4;

#define DEV __device__ __forceinline__

DEV ushort_t f2bf(float x) {
  union { float f; unsigned u; } v; v.f = x;
  unsigned r = v.u + 0x7fffu + ((v.u >> 16) & 1u);
  return (ushort_t)(r >> 16);
}
DEV float bf2f(ushort_t b) {
  union { unsigned u; float f; } v; v.u = ((unsigned)b) << 16; return v.f;
}
DEV float sigf(float x) { return 1.f / (1.f + __expf(-x)); }

// ---------------- ws layout (bytes), total 0x8600000 = 134 MiB ----------------
#define OFF_WIT   0x0u        // WiT_perm  [2048][256] bf16   (1 MiB)
#define OFF_WHT   0x100000u   // WhT_perm  [2048][512] bf16   (2 MiB)
#define OFF_QKVT  0x300000u   // QKVT      [1024][512] bf16   (1 MiB)
#define OFF_WOT   0x400000u   // WoT       [512][512]  bf16   (0.5 MiB)
#define OFF_WDT   0x480000u   // WdT       [256][512]  bf16   (0.25 MiB)
#define OFF_BP    0x4C0000u   // bP        [2048] f32
#define OFF_HB0   0x500000u   // h ping    [128][512] bf16
#define OFF_HB1   0x520000u   // h pong
#define OFF_CST   0x540000u   // legacy zero region (c lives in registers)
#define OFF_CNT   0x580000u   // barrier counters [2][256] u32 (zeroed by prep)
#define OFF_SERT  0x600000u   // seriesT [128][256][256] bf16, 16 MiB (dead after LSTM)
#define OFF_HID   0x1600000u  // hid bf16 [32768][512] rows=(b,d,t), 32 MiB (alive to end)
#define OFF_NORM  0x3600000u  // normed bf16 [32768][512] rows=(b,t,d) (LN->QKV)
#define OFF_QB    0x5600000u  // q bf16 [32768][512] 32 MiB (QKV->attn)
#define OFF_KB    0x600000u   // k bf16 [32768][256] 16 MiB over dead sert (QKV->attn)
#define OFF_VB    0x7600000u  // v bf16 [32768][256] 16 MiB (QKV->attn)
#define OFF_O     0x3600000u  // attn out bf16 [32768][512] over dead normed (attn->Wo)
#define OFF_MIX   0x5600000u  // mix bf16 [32768][512] over dead qb (Wo->final)

// ---------------- prep: weight permute/transpose/bf16 + state zero ----------------
// perm j' = 4u+g (gate quads adjacent): WiT_perm[j'][i] = Wi[i][512g+u]
__global__ __launch_bounds__(256) void prep_kernel(
    const float* Wi, const float* Wh, const float* Wq, const float* Wk,
    const float* Wv, const float* Wo, const float* Wd, const float* b,
    char* ws) {
  unsigned i = blockIdx.x * 256 + threadIdx.x;
  if (i < 524288u) {                       // WiT
    unsigned j = i >> 8, ii = i & 255u;
    ((ushort_t*)(ws + OFF_WIT))[i] = f2bf(Wi[ii * 2048u + 512u * (j & 3u) + (j >> 2)]);
  } else if (i < 1572864u) {               // WhT
    unsigned x = i - 524288u; unsigned j = x >> 9, k = x & 511u;
    ((ushort_t*)(ws + OFF_WHT))[x] = f2bf(Wh[(size_t)k * 2048u + 512u * (j & 3u) + (j >> 2)]);
  } else if (i < 2097152u) {               // QKVT = [WqT|WkT|WvT]
    unsigned x = i - 1572864u; unsigned j = x >> 9, k = x & 511u;
    float v = (j < 512u) ? Wq[k * 512u + j] : (j < 768u) ? Wk[k * 256u + (j - 512u)]
                                                          : Wv[k * 256u + (j - 768u)];
    ((ushort_t*)(ws + OFF_QKVT))[x] = f2bf(v);
  } else if (i < 2359296u) {               // WoT
    unsigned x = i - 2097152u; unsigned j = x >> 9, k = x & 511u;
    ((ushort_t*)(ws + OFF_WOT))[x] = f2bf(Wo[k * 512u + j]);
  } else if (i < 2490368u) {               // WdT
    unsigned x = i - 2359296u; unsigned j = x >> 9, k = x & 511u;
    ((ushort_t*)(ws + OFF_WDT))[x] = f2bf(Wd[k * 256u + j]);
  } else if (i < 2492416u) {               // bP
    unsigned x = i - 2490368u;
    ((float*)(ws + OFF_BP))[x] = b[512u * (x & 3u) + (x >> 2)];
  } else if (i < 2623488u) {               // hb0+hb1 zero
    unsigned x = i - 2492416u;
    ((ushort_t*)(ws + OFF_HB0))[x] = 0;
  } else if (i < 2754560u) {               // legacy c zero
    unsigned x = i - 2623488u;
    ((float*)(ws + OFF_CST))[x] = 0.f;
  } else if (i < 2755072u) {               // barrier counters zero
    unsigned x = i - 2754560u;
    ((unsigned*)(ws + OFF_CNT))[x] = 0u;
  }
}

// ---------------- seriesT: [n][s][i] = bf16(series[n][i][s]) ----------------
__global__ __launch_bounds__(256) void transpose_kernel(const float* series, ushort_t* sert) {
  __shared__ __align__(16) float tl[64][65];
  int n = blockIdx.x;
  int i0 = (blockIdx.y & 3) * 64, s0 = (blockIdx.y >> 2) * 64;
  int tc = threadIdx.x & 63, tr = threadIdx.x >> 6;
  const float* src = series + (size_t)n * 65536u;
#pragma unroll
  for (int p = 0; p < 16; ++p) {
    int r = p * 4 + tr;
    tl[r][tc] = src[(size_t)(i0 + r) * 256u + s0 + tc];
  }
  __syncthreads();
  ushort_t* dst = sert + (size_t)n * 65536u;
#pragma unroll
  for (int p = 0; p < 16; ++p) {
    int sr = p * 4 + tr;
    dst[(size_t)(s0 + sr) * 256u + i0 + tc] = f2bf(tl[tc][sr]);
  }
}

// ------------- generic bf16 MFMA GEMM, 64x64 tile, BK=256 K-passes, 64KiB LDS -------------
// MODE 1: bf16 out split q/k/v (NTOT=1024); MODE 2: bf16 out (NTOT=512);
// MODE 3: A = bf16(hid[m] + mix[n2(m)]), f32 out (NTOT=256)
template <int K, int NTOT, int MODE>
__global__ __launch_bounds__(256) void gemm_kernel(
    const ushort_t* A, const ushort_t* BT, const float* bias,
    ushort_t* outb, ushort_t* ob1, ushort_t* ob2, float* outf,
    const ushort_t* Ahid, const ushort_t* Amix, int t0) {
  __shared__ __align__(16) unsigned char smem[128 * 512];
  const int tid = threadIdx.x;
  const int m0 = blockIdx.x * 64;
  const int j0 = blockIdx.y * 64;
  const int w = tid >> 6, l = tid & 63;
  const int lo16 = l & 15, hi4 = l >> 4;
  f32x4 acc[4];
#pragma unroll
  for (int s = 0; s < 4; ++s) acc[s] = (f32x4)(0.f);

  for (int kt = 0; kt < K / 256; ++kt) {
#pragma unroll
    for (int it = 0; it < 16; ++it) {
      int ci = it * 256 + tid;
      int r = ci >> 5, cb = ci & 31;
      bf16x8 val;
      if (MODE == 3 && r < 64) {
        int m = m0 + r;
        int bb = m >> 11, dd = (m >> 8) & 7, tt = m & 255;
        int n2 = ((bb << 8) + tt) * 8 + dd;
        const ushort_t* hp = Ahid + (size_t)m * 512u + kt * 256 + cb * 8;
        const ushort_t* mp = Amix + (size_t)n2 * 512u + kt * 256 + cb * 8;
#pragma unroll
        for (int j = 0; j < 8; ++j) val[j] = (short)f2bf(bf2f(hp[j]) + bf2f(mp[j]));
      } else if (r < 64) {
        val = *(const bf16x8*)(A + (size_t)(m0 + r) * K + kt * 256 + cb * 8);
      } else {
        val = *(const bf16x8*)(BT + (size_t)(j0 + (r - 64)) * K + kt * 256 + cb * 8);
      }
      int rr = r & 63;
      unsigned char* base = smem + ((r < 64) ? 0 : 64 * 512);
      *(bf16x8*)(base + rr * 512 + ((cb * 16) ^ ((rr & 7) << 4))) = val;
    }
    __syncthreads();

    const unsigned char* As = smem;
    const unsigned char* Bs = smem + 64 * 512;
    const int rB = 16 * w + lo16;
    const unsigned char* bbase = Bs + rB * 512;
    const int bswz = (rB & 7) << 4;
    const int aswz = (lo16 & 7) << 4;
#pragma unroll
    for (int kk = 0; kk < 256; kk += 32) {
      const int kb = kk * 2 + hi4 * 16;
      bf16x8 bf = *(const bf16x8*)(bbase + (kb ^ bswz));
#pragma unroll
      for (int s = 0; s < 4; ++s) {
        const int rA = 16 * s + lo16;
        bf16x8 af = *(const bf16x8*)(As + rA * 512 + (kb ^ aswz));
        acc[s] = __builtin_amdgcn_mfma_f32_16x16x32_bf16(af, bf, acc[s], 0, 0, 0);
      }
    }
    __syncthreads();
  }

  const int col = j0 + 16 * w + lo16;
#pragma unroll
  for (int s = 0; s < 4; ++s) {
#pragma unroll
    for (int jj = 0; jj < 4; ++jj) {
      int m = m0 + 16 * s + hi4 * 4 + jj;
      float v = acc[s][jj];
      if (MODE == 1) {
        if (col < 512) outb[(size_t)m * 512u + col] = f2bf(v);
        else if (col < 768) ob1[(size_t)m * 256u + (col - 512)] = f2bf(v);
        else ob2[(size_t)m * 256u + (col - 768)] = f2bf(v);
      } else if (MODE == 2) {
        outb[(size_t)m * NTOT + col] = f2bf(v);
      } else {
        outf[(size_t)m * NTOT + col] = v;
      }
    }
  }
}

// ------------- persistent LSTM scan: 1 cooperative launch, custom per-rowgroup barrier ----
// grid 256 = 2 rg x 128 cg, 256 thr. Block: 64 rows x 16 gate cols. Same lane algebra as
// round-7 step kernel (verified): swapped MFMA, A=W col frags, B=[h|x] row frags.
// W (24 frags) + c + x-prefetch live in REGISTERS across all 256 steps; only h is
// exchanged through memory. Barrier: release-fence -> atomicAdd -> bounded spin
// (target 128 per row group) -> acquire-fence. Registers survive the cache invalidate.
__global__ __launch_bounds__(256, 1) void lstm_scan_kernel(
    ushort_t* h0, ushort_t* h1, const ushort_t* wht, const ushort_t* wit,
    const float* bp, const ushort_t* sert, ushort_t* hidb, unsigned* cnt) {
  const int tid = threadIdx.x;
  const int blk = blockIdx.x;
  const int rg = blk >> 7;
  const int n0 = rg * 64;
  const int j0 = (blk & 127) * 16;
  const int w = tid >> 6, l = tid & 63;
  const int lo16 = l & 15, hi4 = l >> 4;
  const int row = n0 + w * 16 + lo16;  // batch row (B operand / D col)
  const int colA = j0 + lo16;          // gate col (A operand)

  // persistent W fragments (96 VGPR)
  const ushort_t* wh_p = wht + (size_t)colA * 512u + hi4 * 8;
  const ushort_t* wi_p = wit + (size_t)colA * 256u + hi4 * 8;
  bf16x8 wr[16], wir[8];
#pragma unroll
  for (int i = 0; i < 16; ++i) wr[i] = *(const bf16x8*)(wh_p + i * 32);
#pragma unroll
  for (int i = 0; i < 8; ++i) wir[i] = *(const bf16x8*)(wi_p + i * 32);

  // gate identity: lane owns unit u of its row; c in register
  const int u = (j0 >> 2) + hi4;
  const float4 b4 = *(const float4*)(bp + j0 + 4 * hi4);
  float creg = 0.f;
  unsigned* mycnt = cnt + rg * 256;

  const ushort_t* hrow0 = h0 + (size_t)row * 512u + hi4 * 8;
  const ushort_t* hrow1 = h1 + (size_t)row * 512u + hi4 * 8;
  const ushort_t* xrow = sert + (size_t)row * 65536u + hi4 * 8;
  ushort_t* hn0 = h0 + (size_t)row * 512u + u;
  ushort_t* hn1 = h1 + (size_t)row * 512u + u;
  ushort_t* hidp = hidb + (size_t)row * 131072u + u;  // + t*512

  // x prefetch for t=0
  bf16x8 xf[8];
#pragma unroll
  for (int i = 0; i < 8; ++i) xf[i] = *(const bf16x8*)(xrow + i * 32);

  for (int t = 0; t < 256; ++t) {
    const ushort_t* hr = (t & 1) ? hrow1 : hrow0;
    f32x4 acc = (f32x4)(0.f);
#pragma unroll
    for (int i = 0; i < 16; ++i) {
      bf16x8 bf = *(const bf16x8*)(hr + i * 32);
      acc = __builtin_amdgcn_mfma_f32_16x16x32_bf16(wr[i], bf, acc, 0, 0, 0);
    }
#pragma unroll
    for (int i = 0; i < 8; ++i)
      acc = __builtin_amdgcn_mfma_f32_16x16x32_bf16(wir[i], xf[i], acc, 0, 0, 0);

    float ig = sigf(acc[0] + b4.x);
    float fg = sigf(acc[1] + b4.y);
    float gg = tanhf(acc[2] + b4.z);
    float og = sigf(acc[3] + b4.w);
    creg = fg * creg + ig * gg;
    float h = og * tanhf(creg);
    ushort_t hb16 = f2bf(h);
    *((t & 1) ? hn0 : hn1) = hb16;
    hidp[(size_t)t * 512u] = hb16;

    if (t < 255) {
      // prefetch next x into registers before the barrier (survives invalidate)
#pragma unroll
      for (int i = 0; i < 8; ++i)
        xf[i] = *(const bf16x8*)(xrow + (size_t)(t + 1) * 256u + i * 32);
      __builtin_amdgcn_fence(__ATOMIC_RELEASE, "agent");  // waitcnt + L2 writeback
      __syncthreads();
      if (tid == 0) {
        __hip_atomic_fetch_add(&mycnt[t], 1u, __ATOMIC_RELAXED, __HIP_MEMORY_SCOPE_AGENT);
        unsigned v; int it = 0;
        do {
          v = __hip_atomic_load(&mycnt[t], __ATOMIC_RELAXED, __HIP_MEMORY_SCOPE_AGENT);
          __builtin_amdgcn_s_sleep(1);
        } while (v < 128u && ++it < 200000);
      }
      __syncthreads();
      __builtin_amdgcn_fence(__ATOMIC_ACQUIRE, "agent");  // invalidate stale caches
    }
  }
}

// -------- LayerNorm: hid bf16 row m=(b,d,t) -> normed bf16 row n2=(b,t,d) --------
__global__ __launch_bounds__(256) void ln_kernel(const ushort_t* hidb, const float* sc,
                                                 const float* bi, ushort_t* normed) {
  int row = blockIdx.x * 4 + (threadIdx.x >> 6);
  int l = threadIdx.x & 63;
  bf16x8 hv = *(const bf16x8*)(hidb + (size_t)row * 512u + l * 8);
  float v[8];
  float s1 = 0.f, s2 = 0.f;
#pragma unroll
  for (int j = 0; j < 8; ++j) {
    v[j] = bf2f((ushort_t)hv[j]);
    s1 += v[j]; s2 += v[j] * v[j];
  }
#pragma unroll
  for (int off = 1; off < 64; off <<= 1) {
    s1 += __shfl_xor(s1, off);
    s2 += __shfl_xor(s2, off);
  }
  float mu = s1 * (1.f / 512.f);
  float var = s2 * (1.f / 512.f) - mu * mu;
  float rs = rsqrtf(var + 1e-6f);
  int bb = row >> 11, dd = (row >> 8) & 7, tt = row & 255;
  int n2 = ((bb << 8) + tt) * 8 + dd;
  bf16x8 o;
#pragma unroll
  for (int j = 0; j < 8; ++j)
    o[j] = (short)f2bf((v[j] - mu) * rs * sc[l * 8 + j] + bi[l * 8 + j]);
  *(bf16x8*)(normed + (size_t)n2 * 512u + l * 8) = o;
}

// -------- attention: per (bt, head) 8x8 GQA + qk_norm, bf16 in/out --------
__global__ __launch_bounds__(256) void attn_kernel(const ushort_t* qb, const ushort_t* kb,
                                                   const ushort_t* vb, const float* qn,
                                                   const float* kn, ushort_t* ob) {
  __shared__ __align__(16) float sm[4][3240];
  const int n = blockIdx.x;
  const int w = threadIdx.x >> 6;
  const int l = threadIdx.x & 63;
  const int dq = l >> 3, c = l & 7;
  float* q_s = &sm[w][0];
  float* k_s = q_s + 1056;
  float* v_s = k_s + 1056;
  float* a_s = v_s + 1056;
  const int hk = w >> 1;

  {
    const ushort_t* src = qb + ((size_t)n * 8u + dq) * 512u + w * 128 + c * 16;
    bf16x8 a0 = *(const bf16x8*)src, a1 = *(const bf16x8*)(src + 8);
    float v[16], s1 = 0.f, s2 = 0.f;
#pragma unroll
    for (int j = 0; j < 16; ++j) {
      v[j] = bf2f((ushort_t)(j < 8 ? a0[j] : a1[j - 8]));
      s1 += v[j]; s2 += v[j] * v[j];
    }
    for (int off = 1; off < 8; off <<= 1) { s1 += __shfl_xor(s1, off); s2 += __shfl_xor(s2, off); }
    float mu = s1 * (1.f / 128.f);
    float rs = rsqrtf(s2 * (1.f / 128.f) - mu * mu + 1e-6f);
#pragma unroll
    for (int j = 0; j < 16; ++j)
      q_s[dq * 132 + c * 16 + j] = (v[j] - mu) * rs * qn[c * 16 + j] * 0.08838834764831845f;
  }
  {
    const ushort_t* src = kb + ((size_t)n * 8u + dq) * 256u + hk * 128 + c * 16;
    bf16x8 a0 = *(const bf16x8*)src, a1 = *(const bf16x8*)(src + 8);
    float v[16], s1 = 0.f, s2 = 0.f;
#pragma unroll
    for (int j = 0; j < 16; ++j) {
      v[j] = bf2f((ushort_t)(j < 8 ? a0[j] : a1[j - 8]));
      s1 += v[j]; s2 += v[j] * v[j];
    }
    for (int off = 1; off < 8; off <<= 1) { s1 += __shfl_xor(s1, off); s2 += __shfl_xor(s2, off); }
    float mu = s1 * (1.f / 128.f);
    float rs = rsqrtf(s2 * (1.f / 128.f) - mu * mu + 1e-6f);
#pragma unroll
    for (int j = 0; j < 16; ++j)
      k_s[dq * 132 + c * 16 + j] = (v[j] - mu) * rs * kn[c * 16 + j];
  }
  {
    const ushort_t* src = vb + ((size_t)n * 8u + dq) * 256u + hk * 128 + c * 16;
    bf16x8 a0 = *(const bf16x8*)src, a1 = *(const bf16x8*)(src + 8);
#pragma unroll
    for (int j = 0; j < 16; ++j)
      v_s[dq * 132 + c * 16 + j] = bf2f((ushort_t)(j < 8 ? a0[j] : a1[j - 8]));
  }
  __syncthreads();

  float scv = 0.f;
#pragma unroll 16
  for (int i = 0; i < 128; ++i) scv += q_s[dq * 132 + i] * k_s[c * 132 + i];
  float mx = scv;
  for (int off = 1; off < 8; off <<= 1) mx = fmaxf(mx, __shfl_xor(mx, off));
  float e = __expf(scv - mx);
  float sum = e;
  for (int off = 1; off < 8; off <<= 1) sum += __shfl_xor(sum, off);
  a_s[dq * 9 + c] = e / sum;
  __syncthreads();

  float o[16];
#pragma unroll
  for (int j = 0; j < 16; ++j) o[j] = 0.f;
#pragma unroll
  for (int dk = 0; dk < 8; ++dk) {
    float a = a_s[dq * 9 + dk];
#pragma unroll
    for (int j = 0; j < 16; ++j) o[j] += a * v_s[dk * 132 + c * 16 + j];
  }
  unsigned* dst = (unsigned*)(ob + ((size_t)n * 8u + dq) * 512u + w * 128 + c * 16);
#pragma unroll
  for (int j = 0; j < 8; ++j)
    dst[j] = (unsigned)f2bf(o[2 * j]) | ((unsigned)f2bf(o[2 * j + 1]) << 16);
}

// ---------------- launch ----------------
extern "C" void kernel_launch(void* const* d_in, const int* in_sizes, int n_in,
                              void* d_out, int out_size, void* d_ws, size_t ws_size,
                              hipStream_t stream) {
  const float* series = (const float*)d_in[0];
  const float* Wi = (const float*)d_in[1];
  const float* Wh = (const float*)d_in[2];
  const float* b = (const float*)d_in[3];
  const float* lns = (const float*)d_in[4];
  const float* lnb = (const float*)d_in[5];
  const float* Wq = (const float*)d_in[6];
  const float* Wk = (const float*)d_in[7];
  const float* Wv = (const float*)d_in[8];
  const float* qn = (const float*)d_in[9];
  const float* kn = (const float*)d_in[10];
  const float* Wo = (const float*)d_in[11];
  const float* Wd = (const float*)d_in[12];
  char* ws = (char*)d_ws;

  ushort_t* wit = (ushort_t*)(ws + OFF_WIT);
  ushort_t* wht = (ushort_t*)(ws + OFF_WHT);
  ushort_t* qkvt = (ushort_t*)(ws + OFF_QKVT);
  ushort_t* wot = (ushort_t*)(ws + OFF_WOT);
  ushort_t* wdt = (ushort_t*)(ws + OFF_WDT);
  float* bp = (float*)(ws + OFF_BP);
  ushort_t* hb0 = (ushort_t*)(ws + OFF_HB0);
  ushort_t* hb1 = (ushort_t*)(ws + OFF_HB1);
  unsigned* cnt = (unsigned*)(ws + OFF_CNT);
  ushort_t* sert = (ushort_t*)(ws + OFF_SERT);
  ushort_t* hidb = (ushort_t*)(ws + OFF_HID);
  ushort_t* normed = (ushort_t*)(ws + OFF_NORM);
  ushort_t* qb = (ushort_t*)(ws + OFF_QB);
  ushort_t* kb = (ushort_t*)(ws + OFF_KB);
  ushort_t* vb = (ushort_t*)(ws + OFF_VB);
  ushort_t* ob = (ushort_t*)(ws + OFF_O);
  ushort_t* mixb = (ushort_t*)(ws + OFF_MIX);

  prep_kernel<<<10762, 256, 0, stream>>>(Wi, Wh, Wq, Wk, Wv, Wo, Wd, b, ws);
  transpose_kernel<<<dim3(128, 16), 256, 0, stream>>>(series, sert);

  // whole LSTM scan: one cooperative launch, hand-rolled per-rowgroup barrier
  void* kargs[] = {(void*)&hb0, (void*)&hb1, (void*)&wht, (void*)&wit,
                   (void*)&bp,  (void*)&sert, (void*)&hidb, (void*)&cnt};
  hipLaunchCooperativeKernel((void*)lstm_scan_kernel, dim3(256), dim3(256),
                             kargs, 0, stream);

  ln_kernel<<<8192, 256, 0, stream>>>(hidb, lns, lnb, normed);

  // q/k/v = normed @ [Wq|Wk|Wv] (bf16 out)
  gemm_kernel<512, 1024, 1><<<dim3(512, 16), 256, 0, stream>>>(
      normed, qkvt, nullptr, qb, kb, vb, nullptr, nullptr, nullptr, 0);

  attn_kernel<<<4096, 256, 0, stream>>>(qb, kb, vb, qn, kn, ob);

  // mix = o @ Wo -> bf16
  gemm_kernel<512, 512, 2><<<dim3(512, 8), 256, 0, stream>>>(
      ob, wot, nullptr, mixb, nullptr, nullptr, nullptr, nullptr, nullptr, 0);

  // out = (hid + mix) @ Wdown -> f32 d_out
  gemm_kernel<512, 256, 3><<<dim3(512, 4), 256, 0, stream>>>(
      nullptr, wdt, nullptr, nullptr, nullptr, nullptr, (float*)d_out, hidb, mixb, 0);
}